// Round 11
// baseline (926.110 us; speedup 1.0000x reference)
//
#include <hip/hip_runtime.h>
#include <math.h>

#define NN 50000
#define NE 1600000
#define NG 256
#define IND 128
#define HID 64
#define NREL 3
#define SLOPE 0.2f
#define XRS 192        // XR row stride in elements (3 relations * 64)
#define NRS 832        // node_rep row stride = 13*64
#define W0SZ (192*128)           // layer-0 Wt table, shorts
#define WLSZ (192*64)            // layer-1..12 Wt table, shorts
#define WTOT (W0SZ + 12*WLSZ)    // 172032 shorts
#define NBKT 49                  // ceil(NN/1024)
#define ACHUNK 4096              // edges per pass-A block

typedef short bf16x8 __attribute__((ext_vector_type(8)));
typedef float f32x4 __attribute__((ext_vector_type(4)));

__device__ __forceinline__ float wred_max(float v){
  #pragma unroll
  for (int o = 32; o; o >>= 1) v = fmaxf(v, __shfl_xor(v, o));
  return v;
}
__device__ __forceinline__ float wred_sum(float v){
  #pragma unroll
  for (int o = 32; o; o >>= 1) v += __shfl_xor(v, o);
  return v;
}

__device__ __forceinline__ unsigned short f2bf(float f){
  unsigned int u = __float_as_uint(f);
  u = (u + 0x7FFFu + ((u >> 16) & 1u)) >> 16;   // RNE
  return (unsigned short)u;
}
__device__ __forceinline__ float bf2f(unsigned short h){
  return __uint_as_float(((unsigned int)h) << 16);
}

// ---- CSR build: two-level counting sort (L2-resident write windows) ---------

__global__ __launch_bounds__(256) void bhistA_kernel(const int* __restrict__ dst,
                                                     int* __restrict__ bkt_cnt){
  __shared__ int h[64];
  int tid = threadIdx.x;
  if (tid < 64) h[tid] = 0;
  __syncthreads();
  int e0 = blockIdx.x * ACHUNK;
  int e1 = min(e0 + ACHUNK, NE);
  for (int i = e0 + tid; i < e1; i += 256)
    atomicAdd(&h[dst[i] >> 10], 1);
  __syncthreads();
  if (tid < 64 && h[tid] > 0) atomicAdd(&bkt_cnt[tid], h[tid]);
}

__global__ void bscan_kernel(const int* __restrict__ bkt_cnt, int* __restrict__ bkt_base,
                             int* __restrict__ bkt_fill, int* __restrict__ rowp){
  int tid = threadIdx.x;  // 64
  int v = (tid < NBKT) ? bkt_cnt[tid] : 0;
  int x = v;
  #pragma unroll
  for (int o = 1; o < 64; o <<= 1){ int t = __shfl_up(x, o); if (tid >= o) x += t; }
  int excl = x - v;
  if (tid <= NBKT){ bkt_base[tid] = excl; bkt_fill[tid] = excl; }
  if (tid == 0) rowp[NN] = NE;
}

// packed record: dlocal(10b)<<18 | et(2b)<<16 | src(16b)
__global__ __launch_bounds__(256) void bscatA_kernel(
    const int* __restrict__ src, const int* __restrict__ dst, const int* __restrict__ et,
    int* __restrict__ bkt_fill, unsigned int* __restrict__ ebkt){
  __shared__ int h[64];
  __shared__ int bbase[64];
  int tid = threadIdx.x;
  if (tid < 64) h[tid] = 0;
  __syncthreads();
  int e0 = blockIdx.x * ACHUNK;
  int e1 = min(e0 + ACHUNK, NE);
  for (int i = e0 + tid; i < e1; i += 256)
    atomicAdd(&h[dst[i] >> 10], 1);
  __syncthreads();
  if (tid < 64) bbase[tid] = (h[tid] > 0) ? atomicAdd(&bkt_fill[tid], h[tid]) : 0;
  __syncthreads();
  if (tid < 64) h[tid] = 0;   // reuse as chunk-local fill
  __syncthreads();
  for (int i = e0 + tid; i < e1; i += 256){
    int d = dst[i];
    int b = d >> 10;
    int pos = atomicAdd(&h[b], 1);
    ebkt[bbase[b] + pos] =
        ((unsigned int)(d & 1023) << 18) | ((unsigned int)(et[i] & 3) << 16) | (unsigned int)src[i];
  }
}

__global__ __launch_bounds__(1024) void bsortB_kernel(
    const unsigned int* __restrict__ ebkt, const int* __restrict__ bkt_base,
    int* __restrict__ rowp, int* __restrict__ csr){
  __shared__ int cnt[1024];
  __shared__ int ws[16];
  int b = blockIdx.x, tid = threadIdx.x;
  int beg = bkt_base[b], end = bkt_base[b + 1];
  cnt[tid] = 0;
  __syncthreads();
  for (int i = beg + tid; i < end; i += 1024)
    atomicAdd(&cnt[(ebkt[i] >> 18) & 1023], 1);
  __syncthreads();
  int v = cnt[tid];
  int lane = tid & 63, wv = tid >> 6;
  int x = v;
  #pragma unroll
  for (int o = 1; o < 64; o <<= 1){ int t = __shfl_up(x, o); if (lane >= o) x += t; }
  if (lane == 63) ws[wv] = x;
  __syncthreads();
  if (tid < 16){
    int y = ws[tid];
    #pragma unroll
    for (int o = 1; o < 16; o <<= 1){ int t = __shfl_up(y, o); if (tid >= o) y += t; }
    ws[tid] = y;
  }
  __syncthreads();
  int excl = x + ((wv > 0) ? ws[wv - 1] : 0) - v;
  int node = b * 1024 + tid;
  if (node < NN) rowp[node] = beg + excl;
  cnt[tid] = excl;     // reuse as per-dst fill (relative to beg)
  __syncthreads();
  for (int i = beg + tid; i < end; i += 1024){
    unsigned int p = ebkt[i];
    int dl = (p >> 18) & 1023;
    int pos = atomicAdd(&cnt[dl], 1);
    csr[beg + pos] = (int)(p & 0x3FFFFu);   // src | et<<16
  }
}

// graph boundaries from sorted batch_index
__global__ void gstart_kernel(const int* __restrict__ batch, int* __restrict__ gst){
  int n = blockIdx.x * blockDim.x + threadIdx.x;
  if (n > NN) return;
  int bc = (n < NN) ? batch[n] : NG;
  int bp = (n == 0) ? -1 : batch[n - 1];
  for (int g = bp + 1; g <= bc; ++g) gst[g] = n;
}

// ---- batched weight prep for ALL 13 layers ---------------------------------
__global__ void wprep13_kernel(const float* __restrict__ Wf, const float* __restrict__ Ws,
                               unsigned short* __restrict__ Wtg13){
  int i = blockIdx.x * blockDim.x + threadIdx.x;
  if (i >= WTOT) return;
  int j, K; size_t base; const float* W;
  if (i < W0SZ){ j = i; K = IND; base = 0; W = Wf; }
  else {
    int t = i - W0SZ;
    int l = t / WLSZ;                 // 0..11 -> layer l+1
    j = t - l * WLSZ; K = HID;
    base = W0SZ + (size_t)l * WLSZ;
    W = Ws + (size_t)l * WLSZ;
  }
  int h = j & 63;
  int k = (j >> 6) % K;
  int r = j / (K * HID);
  Wtg13[base + (size_t)((r << 6) + h) * K + k] = f2bf(W[j]);
}

// ---- MFMA GEMM: XRb[n][f] = bf16( sum_k x[n][k] * W[f][k] ), f = r*64+h ----
// A-op = W (16 features x K), B-op = x (K x 16 rows). Dynamic LDS 192*(K+8).
// For K==64 the x-fragment loads from the bf16 shadow xb (one 16B load).
__global__ __launch_bounds__(256) void mm_kernel(
    const float* __restrict__ xf, const unsigned short* __restrict__ xb,
    int ldx, int K,
    const unsigned short* __restrict__ Wtg,
    const float* __restrict__ qv, const float* __restrict__ kv,
    unsigned short* __restrict__ XRb, float* __restrict__ QK){
  extern __shared__ unsigned short Wt[];   // [192][K+8]
  int wtp = K + 8;
  int tid = threadIdx.x;
  int w = tid >> 6, lane = tid & 63;
  int lrow = lane & 15, kg = lane >> 4;
  int row = blockIdx.x * 64 + w * 16 + lrow;
  int k8s = K >> 3;
  int nb8 = 192 * k8s;
  for (int i = tid; i < nb8; i += 256){
    int col = i / k8s;
    int k8 = (i - col * k8s) << 3;
    *(bf16x8*)&Wt[col * wtp + k8] = *(const bf16x8*)&Wtg[(size_t)col * K + k8];
  }
  __syncthreads();

  f32x4 acc[12];
  #pragma unroll
  for (int t = 0; t < 12; ++t) acc[t] = (f32x4){0.f, 0.f, 0.f, 0.f};

  int ksteps = K >> 5;
  for (int ks = 0; ks < ksteps; ++ks){
    int kk = (ks << 5) + (kg << 3);
    bf16x8 xv;
    #pragma unroll
    for (int j = 0; j < 8; ++j) xv[j] = 0;
    if (row < NN){
      if (xb){                                 // bf16 shadow path (K==64)
        xv = *(const bf16x8*)(xb + (size_t)row * HID + kk);
      } else {                                 // fp32 path (layer 0)
        const float* xp = xf + (size_t)row * ldx + kk;
        float4 v0 = *(const float4*)xp;
        float4 v1 = *(const float4*)(xp + 4);
        xv[0] = (short)f2bf(v0.x); xv[1] = (short)f2bf(v0.y);
        xv[2] = (short)f2bf(v0.z); xv[3] = (short)f2bf(v0.w);
        xv[4] = (short)f2bf(v1.x); xv[5] = (short)f2bf(v1.y);
        xv[6] = (short)f2bf(v1.z); xv[7] = (short)f2bf(v1.w);
      }
    }
    #pragma unroll
    for (int t = 0; t < 12; ++t){
      bf16x8 wf = *(const bf16x8*)&Wt[(t * 16 + lrow) * wtp + kk];
      acc[t] = __builtin_amdgcn_mfma_f32_16x16x32_bf16(wf, xv, acc[t], 0, 0, 0);
    }
  }

  if (row < NN){
    unsigned short* orow = XRb + (size_t)row * XRS;
    #pragma unroll
    for (int t = 0; t < 12; ++t){
      ushort4 o4;
      o4.x = f2bf(acc[t][0]); o4.y = f2bf(acc[t][1]);
      o4.z = f2bf(acc[t][2]); o4.w = f2bf(acc[t][3]);
      *(ushort4*)(orow + t * 16 + (kg << 2)) = o4;
    }
  }

  float pq[3] = {0,0,0}, pk[3] = {0,0,0};
  #pragma unroll
  for (int t = 0; t < 12; ++t){
    int r = t >> 2;
    int hbase = ((t & 3) << 4) + (kg << 2);
    #pragma unroll
    for (int j = 0; j < 4; ++j){
      float qc = qv[hbase + j], kc = kv[hbase + j];
      pq[r] = fmaf(acc[t][j], qc, pq[r]);
      pk[r] = fmaf(acc[t][j], kc, pk[r]);
    }
  }
  #pragma unroll
  for (int o = 16; o < 64; o <<= 1){
    #pragma unroll
    for (int r = 0; r < 3; ++r){
      pq[r] += __shfl_xor(pq[r], o);
      pk[r] += __shfl_xor(pk[r], o);
    }
  }
  if (kg == 0 && row < NN){
    #pragma unroll
    for (int r = 0; r < 3; ++r){
      QK[row * 8 + r] = pq[r];
      QK[row * 8 + 3 + r] = pk[r];
    }
  }
}

// ---- edge softmax + aggregation: one wave per dst node ----------------------
// csr entry: src(16b) | et(2b)<<16. Also writes bf16 shadow xb16[n][64] for
// the next layer's mm B-fragment load.

__global__ __launch_bounds__(256) void edge_kernel(
    const unsigned short* __restrict__ XRb, const float* __restrict__ QK,
    const int* __restrict__ csr, const int* __restrict__ rowp,
    const float* __restrict__ bias, float* __restrict__ out,
    unsigned short* __restrict__ xb16){
  int wid = blockIdx.x * 4 + (threadIdx.x >> 6);
  int lane = threadIdx.x & 63;
  if (wid >= NN) return;
  int beg = rowp[wid], end = rowp[wid + 1];
  int cnt = end - beg;
  float* orow = out + (size_t)wid * NRS;
  unsigned short* xrow = xb16 + (size_t)wid * HID;
  int sub = lane & 7;
  int g   = lane >> 3;
  if (cnt == 0){
    if (lane < 8){
      float4 b0 = *(const float4*)(bias + sub * 8);
      float4 b1 = *(const float4*)(bias + sub * 8 + 4);
      *(float4*)(orow + sub * 8) = b0;
      *(float4*)(orow + sub * 8 + 4) = b1;
      ushort4 s0, s1;
      s0.x = f2bf(b0.x); s0.y = f2bf(b0.y); s0.z = f2bf(b0.z); s0.w = f2bf(b0.w);
      s1.x = f2bf(b1.x); s1.y = f2bf(b1.y); s1.z = f2bf(b1.z); s1.w = f2bf(b1.w);
      *(ushort4*)(xrow + sub * 8) = s0;
      *(ushort4*)(xrow + sub * 8 + 4) = s1;
    }
    return;
  }
  float q0 = QK[wid * 8], q1 = QK[wid * 8 + 1], q2 = QK[wid * 8 + 2];

  if (cnt <= 128){
    float l0 = -INFINITY, l1 = -INFINITY;
    int o0 = 0, o1 = 0;
    {
      int idx = beg + lane;
      if (idx < end){
        int pk = csr[idx];
        int sn = pk & 0xFFFF, et = (pk >> 16) & 3;
        float lg = (et == 0 ? q0 : (et == 1 ? q1 : q2)) + QK[sn * 8 + 3 + et];
        l0 = lg >= 0.f ? lg : lg * SLOPE;
        o0 = sn * XRS + et * HID;
      }
      idx += 64;
      if (idx < end){
        int pk = csr[idx];
        int sn = pk & 0xFFFF, et = (pk >> 16) & 3;
        float lg = (et == 0 ? q0 : (et == 1 ? q1 : q2)) + QK[sn * 8 + 3 + et];
        l1 = lg >= 0.f ? lg : lg * SLOPE;
        o1 = sn * XRS + et * HID;
      }
    }
    float m = wred_max(fmaxf(l0, l1));
    float e0 = __expf(l0 - m), e1 = __expf(l1 - m);
    float s = wred_sum(e0 + e1);
    float inv = 1.f / (s + 1e-16f);
    float w0 = e0 * inv, w1 = e1 * inv;

    const unsigned short* xp = XRb + sub * 8;
    float acc[8] = {};

    float wS[8]; int oS[8];
    #pragma unroll
    for (int e = 0; e < 8; ++e){
      int sl = (e << 3) + g;
      wS[e] = __shfl(w0, sl);
      oS[e] = __shfl(o0, sl);
    }
    int nIt = (min(cnt, 64) + 7) >> 3;
    #pragma unroll
    for (int e = 0; e < 8; ++e){
      uint4 d = *(const uint4*)(xp + oS[e]);
      float we = wS[e];
      acc[0] = fmaf(we, __uint_as_float(d.x << 16), acc[0]);
      acc[1] = fmaf(we, __uint_as_float(d.x & 0xFFFF0000u), acc[1]);
      acc[2] = fmaf(we, __uint_as_float(d.y << 16), acc[2]);
      acc[3] = fmaf(we, __uint_as_float(d.y & 0xFFFF0000u), acc[3]);
      acc[4] = fmaf(we, __uint_as_float(d.z << 16), acc[4]);
      acc[5] = fmaf(we, __uint_as_float(d.z & 0xFFFF0000u), acc[5]);
      acc[6] = fmaf(we, __uint_as_float(d.w << 16), acc[6]);
      acc[7] = fmaf(we, __uint_as_float(d.w & 0xFFFF0000u), acc[7]);
      if (e + 1 >= nIt) break;
    }
    if (cnt > 64){
      #pragma unroll
      for (int e = 0; e < 8; ++e){
        int sl = (e << 3) + g;
        wS[e] = __shfl(w1, sl);
        oS[e] = __shfl(o1, sl);
      }
      int nIt2 = (cnt - 64 + 7) >> 3;
      #pragma unroll
      for (int e = 0; e < 8; ++e){
        uint4 d = *(const uint4*)(xp + oS[e]);
        float we = wS[e];
        acc[0] = fmaf(we, __uint_as_float(d.x << 16), acc[0]);
        acc[1] = fmaf(we, __uint_as_float(d.x & 0xFFFF0000u), acc[1]);
        acc[2] = fmaf(we, __uint_as_float(d.y << 16), acc[2]);
        acc[3] = fmaf(we, __uint_as_float(d.y & 0xFFFF0000u), acc[3]);
        acc[4] = fmaf(we, __uint_as_float(d.z << 16), acc[4]);
        acc[5] = fmaf(we, __uint_as_float(d.z & 0xFFFF0000u), acc[5]);
        acc[6] = fmaf(we, __uint_as_float(d.w << 16), acc[6]);
        acc[7] = fmaf(we, __uint_as_float(d.w & 0xFFFF0000u), acc[7]);
        if (e + 1 >= nIt2) break;
      }
    }
    #pragma unroll
    for (int o = 8; o < 64; o <<= 1)
      #pragma unroll
      for (int j = 0; j < 8; ++j)
        acc[j] += __shfl_xor(acc[j], o);
    if (lane < 8){
      float4 b0 = *(const float4*)(bias + sub * 8);
      float4 b1 = *(const float4*)(bias + sub * 8 + 4);
      float4 r0, r1;
      r0.x = acc[0] + b0.x; r0.y = acc[1] + b0.y; r0.z = acc[2] + b0.z; r0.w = acc[3] + b0.w;
      r1.x = acc[4] + b1.x; r1.y = acc[5] + b1.y; r1.z = acc[6] + b1.z; r1.w = acc[7] + b1.w;
      *(float4*)(orow + sub * 8) = r0;
      *(float4*)(orow + sub * 8 + 4) = r1;
      ushort4 s0, s1;
      s0.x = f2bf(r0.x); s0.y = f2bf(r0.y); s0.z = f2bf(r0.z); s0.w = f2bf(r0.w);
      s1.x = f2bf(r1.x); s1.y = f2bf(r1.y); s1.z = f2bf(r1.z); s1.w = f2bf(r1.w);
      *(ushort4*)(xrow + sub * 8) = s0;
      *(ushort4*)(xrow + sub * 8 + 4) = s1;
    }
    return;
  }

  // ---- fallback: arbitrary degree, online two-pass with recompute ----
  float bv = bias[lane];
  float m = -INFINITY, s = 0.f;
  for (int c = beg; c < end; c += 64){
    int idx = c + lane;
    float l = -INFINITY;
    if (idx < end){
      int pk = csr[idx];
      int sn = pk & 0xFFFF, et = (pk >> 16) & 3;
      float lg = (et == 0 ? q0 : (et == 1 ? q1 : q2)) + QK[sn * 8 + 3 + et];
      l = lg >= 0.f ? lg : lg * SLOPE;
    }
    float mnew = fmaxf(m, wred_max(l));
    float ps = wred_sum((idx < end) ? __expf(l - mnew) : 0.f);
    s = s * __expf(m - mnew) + ps;
    m = mnew;
  }
  float inv = 1.f / (s + 1e-16f);
  float acc = 0.f;
  for (int c = beg; c < end; c += 64){
    int idx = c + lane;
    int off = 0; float wgt = 0.f;
    if (idx < end){
      int pk = csr[idx];
      int sn = pk & 0xFFFF, et = (pk >> 16) & 3;
      float lg = (et == 0 ? q0 : (et == 1 ? q1 : q2)) + QK[sn * 8 + 3 + et];
      float l = lg >= 0.f ? lg : lg * SLOPE;
      wgt = __expf(l - m) * inv;
      off = sn * XRS + et * HID;
    }
    int cc = min(64, end - c);
    #pragma unroll 4
    for (int j = 0; j < cc; ++j){
      float wj = __uint_as_float(__builtin_amdgcn_readlane(__float_as_uint(wgt), j));
      int oj = __builtin_amdgcn_readlane(off, j);
      acc = fmaf(wj, bf2f(XRb[oj + lane]), acc);
    }
  }
  float r = acc + bv;
  orow[lane] = r;
  xrow[lane] = f2bf(r);
}

// ---- graph-level softmax aggregation: SINGLE PASS (online) ------------------
__global__ __launch_bounds__(256) void agg_kernel(
    const float* __restrict__ nr, const int* __restrict__ gst,
    const float* __restrict__ tp, float* __restrict__ out){
  __shared__ float rm[4][64], rs[4][64], ra[4][64];
  int g = blockIdx.x;
  int lane = threadIdx.x & 63;
  int w = threadIdx.x >> 6;
  int f = blockIdx.y * 64 + lane;
  int s = gst[g], e = gst[g + 1];
  float tval = tp[0];
  float m = -INFINITY, ss = 0.f, ac = 0.f;
  for (int n = s + w; n < e; n += 4){
    float v = nr[(size_t)n * NRS + f];
    float vm = v * tval;
    float Mn = fmaxf(m, vm);
    float sc = __expf(m - Mn);
    float ev = __expf(vm - Mn);
    ss = ss * sc + ev;
    ac = ac * sc + v * ev;
    m = Mn;
  }
  rm[w][lane] = m; rs[w][lane] = ss; ra[w][lane] = ac;
  __syncthreads();
  if (w == 0){
    float M = fmaxf(fmaxf(rm[0][lane], rm[1][lane]), fmaxf(rm[2][lane], rm[3][lane]));
    float S = 0.f, A = 0.f;
    #pragma unroll
    for (int i = 0; i < 4; ++i){
      float si = rs[i][lane];
      float sci = (si > 0.f) ? __expf(rm[i][lane] - M) : 0.f;
      S = fmaf(si, sci, S);
      A = fmaf(ra[i][lane], sci, A);
    }
    out[(size_t)g * NRS + f] = A / (S + 1e-16f);
  }
}

// ---- orchestration ----------------------------------------------------------

extern "C" void kernel_launch(void* const* d_in, const int* in_sizes, int n_in,
                              void* d_out, int out_size, void* d_ws, size_t ws_size,
                              hipStream_t stream){
  const float* x0   = (const float*)d_in[0];
  const int*   eidx = (const int*)d_in[1];
  const int*   etyp = (const int*)d_in[2];
  const int*   batch= (const int*)d_in[3];
  const float* Wf   = (const float*)d_in[4];
  const float* qf   = (const float*)d_in[5];
  const float* kf   = (const float*)d_in[6];
  const float* bf   = (const float*)d_in[7];
  const float* Ws   = (const float*)d_in[8];
  const float* qs   = (const float*)d_in[9];
  const float* ks   = (const float*)d_in[10];
  const float* bs   = (const float*)d_in[11];
  const float* tp   = (const float*)d_in[12];

  float* gout = (float*)d_out;                 // [256][832]
  float* nrep = gout + (size_t)NG * NRS;       // [50000][832]

  char* w = (char*)d_ws;
  unsigned short* XRb = (unsigned short*)w; w += (size_t)NN * XRS * 2;  // 19.2 MB
  unsigned short* xb16 = (unsigned short*)w; w += (size_t)NN * HID * 2; // 6.4 MB
  float* QK   = (float*)w;  w += (size_t)NN * 8 * 4;          // 1.6 MB
  unsigned short* Wtg13 = (unsigned short*)w; w += (size_t)WTOT * 2;    // 344 KB
  int*   rowp = (int*)w;    w += (size_t)(NN + 2) * 4;
  int*   gst  = (int*)w;    w += (size_t)(NG + 2) * 4;
  int*   bkt_cnt  = (int*)w; w += 64 * 4;
  int*   bkt_base = (int*)w; w += 64 * 4;
  int*   bkt_fill = (int*)w; w += 64 * 4;
  unsigned int* ebkt = (unsigned int*)w; w += (size_t)NE * 4;  // 6.4 MB
  int*   csr  = (int*)w;    w += (size_t)NE * 4;              // 6.4 MB

  const int* srcv = eidx;
  const int* dstv = eidx + NE;

  const int NAB = (NE + ACHUNK - 1) / ACHUNK;   // 391

  // CSR build (two-level counting sort) + graph boundaries + weight tables
  (void)hipMemsetAsync(bkt_cnt, 0, 64 * 4, stream);
  bhistA_kernel<<<NAB, 256, 0, stream>>>(dstv, bkt_cnt);
  bscan_kernel<<<1, 64, 0, stream>>>(bkt_cnt, bkt_base, bkt_fill, rowp);
  bscatA_kernel<<<NAB, 256, 0, stream>>>(srcv, dstv, etyp, bkt_fill, ebkt);
  bsortB_kernel<<<NBKT, 1024, 0, stream>>>(ebkt, bkt_base, rowp, csr);
  gstart_kernel<<<(NN + 256) / 256, 256, 0, stream>>>(batch, gst);
  wprep13_kernel<<<(WTOT + 255) / 256, 256, 0, stream>>>(Wf, Ws, Wtg13);

  for (int l = 0; l < 13; ++l){
    int K = (l == 0) ? IND : HID;
    const unsigned short* Wtg = Wtg13 + ((l == 0) ? 0 : (W0SZ + (size_t)(l - 1) * WLSZ));
    const float* q  = (l == 0) ? qf : (qs + (size_t)(l - 1) * HID);
    const float* kv = (l == 0) ? kf : (ks + (size_t)(l - 1) * HID);
    const float* b  = (l == 0) ? bf : (bs + (size_t)(l - 1) * HID);
    const float* xf = (l == 0) ? x0 : nullptr;
    const unsigned short* xb = (l == 0) ? nullptr : xb16;
    int ldx = (l == 0) ? IND : NRS;
    size_t shb = (size_t)192 * (K + 8) * 2;
    mm_kernel<<<(NN + 63) / 64, 256, shb, stream>>>(xf, xb, ldx, K, Wtg, q, kv, XRb, QK);
    edge_kernel<<<(NN + 3) / 4, 256, 0, stream>>>(XRb, QK, csr, rowp, b, nrep + (size_t)l * HID, xb16);
  }
  dim3 ag(NG, 13);
  agg_kernel<<<ag, 256, 0, stream>>>(nrep, gst, tp, gout);
}

// Round 12
// 904.024 us; speedup vs baseline: 1.0244x; 1.0244x over previous
//
#include <hip/hip_runtime.h>
#include <math.h>

#define NN 50000
#define NE 1600000
#define NG 256
#define IND 128
#define HID 64
#define NREL 3
#define SLOPE 0.2f
#define XRS 192        // XR row stride in elements (3 relations * 64)
#define NRS 832        // node_rep row stride = 13*64
#define WTP 136        // padded LDS stride for Wt (shorts): mult of 8 -> 16B aligned
#define W0SZ (192*128)           // layer-0 Wt table, shorts
#define WLSZ (192*64)            // layer-1..12 Wt table, shorts
#define WTOT (W0SZ + 12*WLSZ)    // 172032 shorts
#define NBKT 49                  // ceil(NN/1024)
#define ACHUNK 4096              // edges per pass-A block

typedef short bf16x8 __attribute__((ext_vector_type(8)));
typedef float f32x4 __attribute__((ext_vector_type(4)));

__device__ __forceinline__ float wred_max(float v){
  #pragma unroll
  for (int o = 32; o; o >>= 1) v = fmaxf(v, __shfl_xor(v, o));
  return v;
}
__device__ __forceinline__ float wred_sum(float v){
  #pragma unroll
  for (int o = 32; o; o >>= 1) v += __shfl_xor(v, o);
  return v;
}

__device__ __forceinline__ unsigned short f2bf(float f){
  unsigned int u = __float_as_uint(f);
  u = (u + 0x7FFFu + ((u >> 16) & 1u)) >> 16;   // RNE
  return (unsigned short)u;
}
__device__ __forceinline__ float bf2f(unsigned short h){
  return __uint_as_float(((unsigned int)h) << 16);
}

// ---- CSR build: two-level counting sort (L2-resident write windows) ---------

__global__ __launch_bounds__(256) void bhistA_kernel(const int* __restrict__ dst,
                                                     int* __restrict__ bkt_cnt){
  __shared__ int h[64];
  int tid = threadIdx.x;
  if (tid < 64) h[tid] = 0;
  __syncthreads();
  int e0 = blockIdx.x * ACHUNK;
  int e1 = min(e0 + ACHUNK, NE);
  for (int i = e0 + tid; i < e1; i += 256)
    atomicAdd(&h[dst[i] >> 10], 1);
  __syncthreads();
  if (tid < 64 && h[tid] > 0) atomicAdd(&bkt_cnt[tid], h[tid]);
}

__global__ void bscan_kernel(const int* __restrict__ bkt_cnt, int* __restrict__ bkt_base,
                             int* __restrict__ bkt_fill, int* __restrict__ rowp){
  int tid = threadIdx.x;  // 64
  int v = (tid < NBKT) ? bkt_cnt[tid] : 0;
  int x = v;
  #pragma unroll
  for (int o = 1; o < 64; o <<= 1){ int t = __shfl_up(x, o); if (tid >= o) x += t; }
  int excl = x - v;
  if (tid <= NBKT){ bkt_base[tid] = excl; bkt_fill[tid] = excl; }
  if (tid == 0) rowp[NN] = NE;
}

// packed record: dlocal(10b)<<18 | et(2b)<<16 | src(16b)
__global__ __launch_bounds__(256) void bscatA_kernel(
    const int* __restrict__ src, const int* __restrict__ dst, const int* __restrict__ et,
    int* __restrict__ bkt_fill, unsigned int* __restrict__ ebkt){
  __shared__ int h[64];
  __shared__ int bbase[64];
  int tid = threadIdx.x;
  if (tid < 64) h[tid] = 0;
  __syncthreads();
  int e0 = blockIdx.x * ACHUNK;
  int e1 = min(e0 + ACHUNK, NE);
  for (int i = e0 + tid; i < e1; i += 256)
    atomicAdd(&h[dst[i] >> 10], 1);
  __syncthreads();
  if (tid < 64) bbase[tid] = (h[tid] > 0) ? atomicAdd(&bkt_fill[tid], h[tid]) : 0;
  __syncthreads();
  if (tid < 64) h[tid] = 0;   // reuse as chunk-local fill
  __syncthreads();
  for (int i = e0 + tid; i < e1; i += 256){
    int d = dst[i];
    int b = d >> 10;
    int pos = atomicAdd(&h[b], 1);
    ebkt[bbase[b] + pos] =
        ((unsigned int)(d & 1023) << 18) | ((unsigned int)(et[i] & 3) << 16) | (unsigned int)src[i];
  }
}

__global__ __launch_bounds__(1024) void bsortB_kernel(
    const unsigned int* __restrict__ ebkt, const int* __restrict__ bkt_base,
    int* __restrict__ rowp, int* __restrict__ csr){
  __shared__ int cnt[1024];
  __shared__ int ws[16];
  int b = blockIdx.x, tid = threadIdx.x;
  int beg = bkt_base[b], end = bkt_base[b + 1];
  cnt[tid] = 0;
  __syncthreads();
  for (int i = beg + tid; i < end; i += 1024)
    atomicAdd(&cnt[(ebkt[i] >> 18) & 1023], 1);
  __syncthreads();
  int v = cnt[tid];
  int lane = tid & 63, wv = tid >> 6;
  int x = v;
  #pragma unroll
  for (int o = 1; o < 64; o <<= 1){ int t = __shfl_up(x, o); if (lane >= o) x += t; }
  if (lane == 63) ws[wv] = x;
  __syncthreads();
  if (tid < 16){
    int y = ws[tid];
    #pragma unroll
    for (int o = 1; o < 16; o <<= 1){ int t = __shfl_up(y, o); if (tid >= o) y += t; }
    ws[tid] = y;
  }
  __syncthreads();
  int excl = x + ((wv > 0) ? ws[wv - 1] : 0) - v;
  int node = b * 1024 + tid;
  if (node < NN) rowp[node] = beg + excl;
  cnt[tid] = excl;     // reuse as per-dst fill (relative to beg)
  __syncthreads();
  for (int i = beg + tid; i < end; i += 1024){
    unsigned int p = ebkt[i];
    int dl = (p >> 18) & 1023;
    int pos = atomicAdd(&cnt[dl], 1);
    csr[beg + pos] = (int)(p & 0x3FFFFu);   // src | et<<16
  }
}

// graph boundaries from sorted batch_index
__global__ void gstart_kernel(const int* __restrict__ batch, int* __restrict__ gst){
  int n = blockIdx.x * blockDim.x + threadIdx.x;
  if (n > NN) return;
  int bc = (n < NN) ? batch[n] : NG;
  int bp = (n == 0) ? -1 : batch[n - 1];
  for (int g = bp + 1; g <= bc; ++g) gst[g] = n;
}

// ---- batched weight prep for ALL 13 layers ---------------------------------
__global__ void wprep13_kernel(const float* __restrict__ Wf, const float* __restrict__ Ws,
                               unsigned short* __restrict__ Wtg13){
  int i = blockIdx.x * blockDim.x + threadIdx.x;
  if (i >= WTOT) return;
  int j, K; size_t base; const float* W;
  if (i < W0SZ){ j = i; K = IND; base = 0; W = Wf; }
  else {
    int t = i - W0SZ;
    int l = t / WLSZ;                 // 0..11 -> layer l+1
    j = t - l * WLSZ; K = HID;
    base = W0SZ + (size_t)l * WLSZ;
    W = Ws + (size_t)l * WLSZ;
  }
  int h = j & 63;
  int k = (j >> 6) % K;
  int r = j / (K * HID);
  Wtg13[base + (size_t)((r << 6) + h) * K + k] = f2bf(W[j]);
}

// ---- MFMA GEMM: XRb[n][f] = bf16( sum_k x[n][k] * W[f][k] ), f = r*64+h ----
// A-op = W (16 features x K), B-op = x (K x 16 rows).
// D layout: lane&15 = x-row, (lane>>4)*4+reg = feature  -> packed ushort4 C-store.
// Epilogue: QK[n][r] = xr_r . q ; QK[n][3+r] = xr_r . k  (xor-16/32 reduce)
__global__ __launch_bounds__(256) void mm_kernel(
    const float* __restrict__ x, int ldx, int K,
    const unsigned short* __restrict__ Wtg,
    const float* __restrict__ qv, const float* __restrict__ kv,
    unsigned short* __restrict__ XRb, float* __restrict__ QK){
  __shared__ unsigned short Wt[192 * WTP];
  int tid = threadIdx.x;
  int w = tid >> 6, lane = tid & 63;
  int lrow = lane & 15, kg = lane >> 4;
  int row = blockIdx.x * 64 + w * 16 + lrow;
  int k8s = K >> 3;
  int nb8 = 192 * k8s;
  for (int i = tid; i < nb8; i += 256){
    int col = i / k8s;
    int k8 = (i - col * k8s) << 3;
    *(bf16x8*)&Wt[col * WTP + k8] = *(const bf16x8*)&Wtg[(size_t)col * K + k8];
  }
  __syncthreads();

  f32x4 acc[12];
  #pragma unroll
  for (int t = 0; t < 12; ++t) acc[t] = (f32x4){0.f, 0.f, 0.f, 0.f};

  int ksteps = K >> 5;
  for (int ks = 0; ks < ksteps; ++ks){
    int kk = (ks << 5) + (kg << 3);
    bf16x8 xv;
    #pragma unroll
    for (int j = 0; j < 8; ++j) xv[j] = 0;
    if (row < NN){
      const float* xp = x + (size_t)row * ldx + kk;
      float4 v0 = *(const float4*)xp;
      float4 v1 = *(const float4*)(xp + 4);
      xv[0] = (short)f2bf(v0.x); xv[1] = (short)f2bf(v0.y);
      xv[2] = (short)f2bf(v0.z); xv[3] = (short)f2bf(v0.w);
      xv[4] = (short)f2bf(v1.x); xv[5] = (short)f2bf(v1.y);
      xv[6] = (short)f2bf(v1.z); xv[7] = (short)f2bf(v1.w);
    }
    #pragma unroll
    for (int t = 0; t < 12; ++t){
      bf16x8 wf = *(const bf16x8*)&Wt[(t * 16 + lrow) * WTP + kk];
      acc[t] = __builtin_amdgcn_mfma_f32_16x16x32_bf16(wf, xv, acc[t], 0, 0, 0);
    }
  }

  if (row < NN){
    unsigned short* orow = XRb + (size_t)row * XRS;
    #pragma unroll
    for (int t = 0; t < 12; ++t){
      ushort4 o4;
      o4.x = f2bf(acc[t][0]); o4.y = f2bf(acc[t][1]);
      o4.z = f2bf(acc[t][2]); o4.w = f2bf(acc[t][3]);
      *(ushort4*)(orow + t * 16 + (kg << 2)) = o4;
    }
  }

  float pq[3] = {0,0,0}, pk[3] = {0,0,0};
  #pragma unroll
  for (int t = 0; t < 12; ++t){
    int r = t >> 2;
    int hbase = ((t & 3) << 4) + (kg << 2);
    #pragma unroll
    for (int j = 0; j < 4; ++j){
      float qc = qv[hbase + j], kc = kv[hbase + j];
      pq[r] = fmaf(acc[t][j], qc, pq[r]);
      pk[r] = fmaf(acc[t][j], kc, pk[r]);
    }
  }
  #pragma unroll
  for (int o = 16; o < 64; o <<= 1){
    #pragma unroll
    for (int r = 0; r < 3; ++r){
      pq[r] += __shfl_xor(pq[r], o);
      pk[r] += __shfl_xor(pk[r], o);
    }
  }
  if (kg == 0 && row < NN){
    #pragma unroll
    for (int r = 0; r < 3; ++r){
      QK[row * 8 + r] = pq[r];
      QK[row * 8 + 3 + r] = pk[r];
    }
  }
}

// ---- edge softmax + aggregation: one wave per dst node ----------------------
// csr entry: src(16b) | et(2b)<<16

__global__ __launch_bounds__(256) void edge_kernel(
    const unsigned short* __restrict__ XRb, const float* __restrict__ QK,
    const int* __restrict__ csr, const int* __restrict__ rowp,
    const float* __restrict__ bias, float* __restrict__ out){
  int wid = blockIdx.x * 4 + (threadIdx.x >> 6);
  int lane = threadIdx.x & 63;
  if (wid >= NN) return;
  int beg = rowp[wid], end = rowp[wid + 1];
  int cnt = end - beg;
  float* orow = out + (size_t)wid * NRS;
  int sub = lane & 7;
  int g   = lane >> 3;
  if (cnt == 0){
    if (lane < 8){
      float4 b0 = *(const float4*)(bias + sub * 8);
      float4 b1 = *(const float4*)(bias + sub * 8 + 4);
      *(float4*)(orow + sub * 8) = b0;
      *(float4*)(orow + sub * 8 + 4) = b1;
    }
    return;
  }
  float q0 = QK[wid * 8], q1 = QK[wid * 8 + 1], q2 = QK[wid * 8 + 2];

  if (cnt <= 128){
    float l0 = -INFINITY, l1 = -INFINITY;
    int o0 = 0, o1 = 0;
    {
      int idx = beg + lane;
      if (idx < end){
        int pk = csr[idx];
        int sn = pk & 0xFFFF, et = (pk >> 16) & 3;
        float lg = (et == 0 ? q0 : (et == 1 ? q1 : q2)) + QK[sn * 8 + 3 + et];
        l0 = lg >= 0.f ? lg : lg * SLOPE;
        o0 = sn * XRS + et * HID;
      }
      idx += 64;
      if (idx < end){
        int pk = csr[idx];
        int sn = pk & 0xFFFF, et = (pk >> 16) & 3;
        float lg = (et == 0 ? q0 : (et == 1 ? q1 : q2)) + QK[sn * 8 + 3 + et];
        l1 = lg >= 0.f ? lg : lg * SLOPE;
        o1 = sn * XRS + et * HID;
      }
    }
    float m = wred_max(fmaxf(l0, l1));
    float e0 = __expf(l0 - m), e1 = __expf(l1 - m);
    float s = wred_sum(e0 + e1);
    float inv = 1.f / (s + 1e-16f);
    float w0 = e0 * inv, w1 = e1 * inv;

    const unsigned short* xp = XRb + sub * 8;
    float acc[8] = {};

    float wS[8]; int oS[8];
    #pragma unroll
    for (int e = 0; e < 8; ++e){
      int sl = (e << 3) + g;
      wS[e] = __shfl(w0, sl);
      oS[e] = __shfl(o0, sl);
    }
    int nIt = (min(cnt, 64) + 7) >> 3;
    #pragma unroll
    for (int e = 0; e < 8; ++e){
      uint4 d = *(const uint4*)(xp + oS[e]);
      float we = wS[e];
      acc[0] = fmaf(we, __uint_as_float(d.x << 16), acc[0]);
      acc[1] = fmaf(we, __uint_as_float(d.x & 0xFFFF0000u), acc[1]);
      acc[2] = fmaf(we, __uint_as_float(d.y << 16), acc[2]);
      acc[3] = fmaf(we, __uint_as_float(d.y & 0xFFFF0000u), acc[3]);
      acc[4] = fmaf(we, __uint_as_float(d.z << 16), acc[4]);
      acc[5] = fmaf(we, __uint_as_float(d.z & 0xFFFF0000u), acc[5]);
      acc[6] = fmaf(we, __uint_as_float(d.w << 16), acc[6]);
      acc[7] = fmaf(we, __uint_as_float(d.w & 0xFFFF0000u), acc[7]);
      if (e + 1 >= nIt) break;
    }
    if (cnt > 64){
      #pragma unroll
      for (int e = 0; e < 8; ++e){
        int sl = (e << 3) + g;
        wS[e] = __shfl(w1, sl);
        oS[e] = __shfl(o1, sl);
      }
      int nIt2 = (cnt - 64 + 7) >> 3;
      #pragma unroll
      for (int e = 0; e < 8; ++e){
        uint4 d = *(const uint4*)(xp + oS[e]);
        float we = wS[e];
        acc[0] = fmaf(we, __uint_as_float(d.x << 16), acc[0]);
        acc[1] = fmaf(we, __uint_as_float(d.x & 0xFFFF0000u), acc[1]);
        acc[2] = fmaf(we, __uint_as_float(d.y << 16), acc[2]);
        acc[3] = fmaf(we, __uint_as_float(d.y & 0xFFFF0000u), acc[3]);
        acc[4] = fmaf(we, __uint_as_float(d.z << 16), acc[4]);
        acc[5] = fmaf(we, __uint_as_float(d.z & 0xFFFF0000u), acc[5]);
        acc[6] = fmaf(we, __uint_as_float(d.w << 16), acc[6]);
        acc[7] = fmaf(we, __uint_as_float(d.w & 0xFFFF0000u), acc[7]);
        if (e + 1 >= nIt2) break;
      }
    }
    #pragma unroll
    for (int o = 8; o < 64; o <<= 1)
      #pragma unroll
      for (int j = 0; j < 8; ++j)
        acc[j] += __shfl_xor(acc[j], o);
    if (lane < 8){
      float4 b0 = *(const float4*)(bias + sub * 8);
      float4 b1 = *(const float4*)(bias + sub * 8 + 4);
      float4 r0, r1;
      r0.x = acc[0] + b0.x; r0.y = acc[1] + b0.y; r0.z = acc[2] + b0.z; r0.w = acc[3] + b0.w;
      r1.x = acc[4] + b1.x; r1.y = acc[5] + b1.y; r1.z = acc[6] + b1.z; r1.w = acc[7] + b1.w;
      *(float4*)(orow + sub * 8) = r0;
      *(float4*)(orow + sub * 8 + 4) = r1;
    }
    return;
  }

  // ---- fallback: arbitrary degree, online two-pass with recompute ----
  float bv = bias[lane];
  float m = -INFINITY, s = 0.f;
  for (int c = beg; c < end; c += 64){
    int idx = c + lane;
    float l = -INFINITY;
    if (idx < end){
      int pk = csr[idx];
      int sn = pk & 0xFFFF, et = (pk >> 16) & 3;
      float lg = (et == 0 ? q0 : (et == 1 ? q1 : q2)) + QK[sn * 8 + 3 + et];
      l = lg >= 0.f ? lg : lg * SLOPE;
    }
    float mnew = fmaxf(m, wred_max(l));
    float ps = wred_sum((idx < end) ? __expf(l - mnew) : 0.f);
    s = s * __expf(m - mnew) + ps;
    m = mnew;
  }
  float inv = 1.f / (s + 1e-16f);
  float acc = 0.f;
  for (int c = beg; c < end; c += 64){
    int idx = c + lane;
    int off = 0; float wgt = 0.f;
    if (idx < end){
      int pk = csr[idx];
      int sn = pk & 0xFFFF, et = (pk >> 16) & 3;
      float lg = (et == 0 ? q0 : (et == 1 ? q1 : q2)) + QK[sn * 8 + 3 + et];
      float l = lg >= 0.f ? lg : lg * SLOPE;
      wgt = __expf(l - m) * inv;
      off = sn * XRS + et * HID;
    }
    int cc = min(64, end - c);
    #pragma unroll 4
    for (int j = 0; j < cc; ++j){
      float wj = __uint_as_float(__builtin_amdgcn_readlane(__float_as_uint(wgt), j));
      int oj = __builtin_amdgcn_readlane(off, j);
      acc = fmaf(wj, bf2f(XRb[oj + lane]), acc);
    }
  }
  orow[lane] = acc + bv;
}

// ---- graph-level softmax aggregation: SINGLE PASS (online) ------------------
__global__ __launch_bounds__(256) void agg_kernel(
    const float* __restrict__ nr, const int* __restrict__ gst,
    const float* __restrict__ tp, float* __restrict__ out){
  __shared__ float rm[4][64], rs[4][64], ra[4][64];
  int g = blockIdx.x;
  int lane = threadIdx.x & 63;
  int w = threadIdx.x >> 6;
  int f = blockIdx.y * 64 + lane;
  int s = gst[g], e = gst[g + 1];
  float tval = tp[0];
  float m = -INFINITY, ss = 0.f, ac = 0.f;
  for (int n = s + w; n < e; n += 4){
    float v = nr[(size_t)n * NRS + f];
    float vm = v * tval;
    float Mn = fmaxf(m, vm);
    float sc = __expf(m - Mn);
    float ev = __expf(vm - Mn);
    ss = ss * sc + ev;
    ac = ac * sc + v * ev;
    m = Mn;
  }
  rm[w][lane] = m; rs[w][lane] = ss; ra[w][lane] = ac;
  __syncthreads();
  if (w == 0){
    float M = fmaxf(fmaxf(rm[0][lane], rm[1][lane]), fmaxf(rm[2][lane], rm[3][lane]));
    float S = 0.f, A = 0.f;
    #pragma unroll
    for (int i = 0; i < 4; ++i){
      float si = rs[i][lane];
      float sci = (si > 0.f) ? __expf(rm[i][lane] - M) : 0.f;
      S = fmaf(si, sci, S);
      A = fmaf(ra[i][lane], sci, A);
    }
    out[(size_t)g * NRS + f] = A / (S + 1e-16f);
  }
}

// ---- orchestration ----------------------------------------------------------

extern "C" void kernel_launch(void* const* d_in, const int* in_sizes, int n_in,
                              void* d_out, int out_size, void* d_ws, size_t ws_size,
                              hipStream_t stream){
  const float* x0   = (const float*)d_in[0];
  const int*   eidx = (const int*)d_in[1];
  const int*   etyp = (const int*)d_in[2];
  const int*   batch= (const int*)d_in[3];
  const float* Wf   = (const float*)d_in[4];
  const float* qf   = (const float*)d_in[5];
  const float* kf   = (const float*)d_in[6];
  const float* bf   = (const float*)d_in[7];
  const float* Ws   = (const float*)d_in[8];
  const float* qs   = (const float*)d_in[9];
  const float* ks   = (const float*)d_in[10];
  const float* bs   = (const float*)d_in[11];
  const float* tp   = (const float*)d_in[12];

  float* gout = (float*)d_out;                 // [256][832]
  float* nrep = gout + (size_t)NG * NRS;       // [50000][832]

  char* w = (char*)d_ws;
  unsigned short* XRb = (unsigned short*)w; w += (size_t)NN * XRS * 2;  // 19.2 MB
  float* QK   = (float*)w;  w += (size_t)NN * 8 * 4;          // 1.6 MB
  unsigned short* Wtg13 = (unsigned short*)w; w += (size_t)WTOT * 2;    // 344 KB
  int*   rowp = (int*)w;    w += (size_t)(NN + 2) * 4;
  int*   gst  = (int*)w;    w += (size_t)(NG + 2) * 4;
  int*   bkt_cnt  = (int*)w; w += 64 * 4;
  int*   bkt_base = (int*)w; w += 64 * 4;
  int*   bkt_fill = (int*)w; w += 64 * 4;
  unsigned int* ebkt = (unsigned int*)w; w += (size_t)NE * 4;  // 6.4 MB
  int*   csr  = (int*)w;    w += (size_t)NE * 4;              // 6.4 MB

  const int* srcv = eidx;
  const int* dstv = eidx + NE;

  const int NAB = (NE + ACHUNK - 1) / ACHUNK;   // 391

  // CSR build (two-level counting sort) + graph boundaries + weight tables
  (void)hipMemsetAsync(bkt_cnt, 0, 64 * 4, stream);
  bhistA_kernel<<<NAB, 256, 0, stream>>>(dstv, bkt_cnt);
  bscan_kernel<<<1, 64, 0, stream>>>(bkt_cnt, bkt_base, bkt_fill, rowp);
  bscatA_kernel<<<NAB, 256, 0, stream>>>(srcv, dstv, etyp, bkt_fill, ebkt);
  bsortB_kernel<<<NBKT, 1024, 0, stream>>>(ebkt, bkt_base, rowp, csr);
  gstart_kernel<<<(NN + 256) / 256, 256, 0, stream>>>(batch, gst);
  wprep13_kernel<<<(WTOT + 255) / 256, 256, 0, stream>>>(Wf, Ws, Wtg13);

  for (int l = 0; l < 13; ++l){
    int K = (l == 0) ? IND : HID;
    const unsigned short* Wtg = Wtg13 + ((l == 0) ? 0 : (W0SZ + (size_t)(l - 1) * WLSZ));
    const float* q  = (l == 0) ? qf : (qs + (size_t)(l - 1) * HID);
    const float* kv = (l == 0) ? kf : (ks + (size_t)(l - 1) * HID);
    const float* b  = (l == 0) ? bf : (bs + (size_t)(l - 1) * HID);
    const float* x  = (l == 0) ? x0 : (nrep + (size_t)(l - 1) * HID);
    int ldx = (l == 0) ? IND : NRS;
    mm_kernel<<<(NN + 63) / 64, 256, 0, stream>>>(x, ldx, K, Wtg, q, kv, XRb, QK);
    edge_kernel<<<(NN + 3) / 4, 256, 0, stream>>>(XRb, QK, csr, rowp, b, nrep + (size_t)l * NRS == nrep + (size_t)l * NRS ? nrep + (size_t)l * HID : nrep + (size_t)l * HID);
  }
  dim3 ag(NG, 13);
  agg_kernel<<<ag, 256, 0, stream>>>(nrep, gst, tp, gout);
}